// Round 7
// baseline (253.669 us; speedup 1.0000x reference)
//
#include <hip/hip_runtime.h>
#include <type_traits>

// GCNEncoder: h1 = relu(SpMM(x@W0) + b0); h2 = relu(SpMM(h1@W1) + b1)
// mean = relu(h2@Wm1+bm1)@Wm2+bm2 ; logvar = relu(h2@Wv1+bv1)@Wv2+bv2
// R5: f16 pipeline, MFMA GEMMs. R7: block-local two-pass binning.
// R8: fused heads, fp32-A GEMM, half8 SpMM. R10: GEMM 2 A-frags/wave.
// R11 (FAILED +26): feature-chunked SpMM — line granularity + XCD
//      replication nullified residency; halved MLP. Gather is ~3.5 TB/s
//      miss-BW-bound (MLP 2x gave only +25%): reduce misses, not latency.
// R12 (FAILED +11): bundled {unroll8, NT hints, fused build} — unattributed.
// R13 (WIN -32.7, 218.9us): fused row-local GEMMs into spmm blocks.
// R14 (FAILED +13.7): degree-balanced rperm — serial tail + sort overhead.
// R15 (WIN -6.1, 212.8us): buildA = blockbin || wconv; buildB = bucketB ||
//      gemm-L1 (co-resident overlap). 8 -> 6 dispatches.
// R16: col-sorted per-row edge segments (insertion sort in bucketB staging).
//      All ~2000 co-resident spmm blocks sweep cols in the same order
//      (order statistics: i-th of d uniforms ~ N*i/d) -> instantaneous
//      gather window ~few MB ~ L2 -> L2 hit rate up, fabric misses down.

typedef _Float16 half8 __attribute__((ext_vector_type(8)));
typedef float floatx4 __attribute__((ext_vector_type(4)));

#define BCAP 2560   // bucket capacity; mean 2048, sigma ~45 -> +11 sigma
#define CHUNK 2048  // edges per binning block
#define RB 128      // rows per bucket

// ---------------------------------------------------------------- gemm L1 (device)
// support1 = x(f32)@W0swz -> f16. R10 structure: 4 waves x 2 A-frags (32 rows),
// NT=8, KS=4. Wswz frag order [(ks*8+nt)*64+lane]*8+j, k=ks*32+quad*8+j,
// n=nt*16+(lane&15). C/D: col=lane&15, row=quad*4+reg (m89-verified).
__device__ void gemm_l1(int bid, const float* __restrict__ A,
                        const _Float16* __restrict__ Wswz,
                        _Float16* __restrict__ C0, int n) {
  const int t = threadIdx.x;
  const int lane = t & 63, wave = t >> 6;
  const int quad = lane >> 4, l16 = lane & 15;
  const int r_base = bid * 128 + wave * 32;

  int arow0 = r_base + l16;
  int arow1 = r_base + 16 + l16;
  if (arow0 >= n) arow0 = n - 1;        // clamp; clamped rows never stored
  if (arow1 >= n) arow1 = n - 1;
  const float* Ap0 = A + (size_t)arow0 * 128 + quad * 8;
  const float* Ap1 = A + (size_t)arow1 * 128 + quad * 8;

  floatx4 acc[2][8] = {};

#pragma unroll
  for (int ks = 0; ks < 4; ++ks) {
    float4 u = *(const float4*)(Ap0 + ks * 32);
    float4 w = *(const float4*)(Ap0 + ks * 32 + 4);
    half8 a0 = half8{(_Float16)u.x, (_Float16)u.y, (_Float16)u.z, (_Float16)u.w,
                     (_Float16)w.x, (_Float16)w.y, (_Float16)w.z, (_Float16)w.w};
    float4 u1 = *(const float4*)(Ap1 + ks * 32);
    float4 w1 = *(const float4*)(Ap1 + ks * 32 + 4);
    half8 a1 = half8{(_Float16)u1.x, (_Float16)u1.y, (_Float16)u1.z, (_Float16)u1.w,
                     (_Float16)w1.x, (_Float16)w1.y, (_Float16)w1.z, (_Float16)w1.w};
#pragma unroll
    for (int nt = 0; nt < 8; ++nt) {
      half8 b = *(const half8*)(Wswz + ((size_t)(ks * 8 + nt) * 64 + lane) * 8);
      acc[0][nt] = __builtin_amdgcn_mfma_f32_16x16x32_f16(a0, b, acc[0][nt], 0, 0, 0);
      acc[1][nt] = __builtin_amdgcn_mfma_f32_16x16x32_f16(a1, b, acc[1][nt], 0, 0, 0);
    }
  }

#pragma unroll
  for (int h = 0; h < 2; ++h) {
#pragma unroll
    for (int nt = 0; nt < 8; ++nt) {
      const int col = nt * 16 + l16;
#pragma unroll
      for (int r = 0; r < 4; ++r) {
        int row = r_base + h * 16 + quad * 4 + r;
        if (row < n) C0[(size_t)row * 128 + col] = (_Float16)acc[h][nt][r];
      }
    }
  }
}

// ---------------------------------------------------------------- buildA
// Blocks [0, binBlocks): block-local two-pass binning.
// Blocks [binBlocks, binBlocks+256): weight swizzle (4 segs).
__global__ __launch_bounds__(256)
void buildA_kernel(const int* __restrict__ rows, const int* __restrict__ cols,
                   const float* __restrict__ vals,
                   int* __restrict__ bcur, uint2* __restrict__ bbuf, int e,
                   int binBlocks,
                   const float* __restrict__ w0, const float* __restrict__ w1,
                   const float* __restrict__ wm1, const float* __restrict__ wv1,
                   const float* __restrict__ wm2, const float* __restrict__ wv2,
                   _Float16* __restrict__ d0, _Float16* __restrict__ d1,
                   _Float16* __restrict__ dh1, _Float16* __restrict__ dh2) {
  __shared__ int cnt[392];
  __shared__ int cur[392];
  const int t = threadIdx.x;

  if (blockIdx.x >= binBlocks) {
    // ---- weight conversion (swizzle to MFMA fragment order)
    int i = (blockIdx.x - binBlocks) * 256 + t;
    if (i >= 65536) return;
    int seg = i >> 14, li = i & 16383;
    int j = li & 7, lane = (li >> 3) & 63, tt = li >> 9;
    int nt = tt & 7, ks = tt >> 3;         // NT=8, KS=4
    int k = ks * 32 + (lane >> 4) * 8 + j;
    int nn = nt * 16 + (lane & 15);
    float v;
    if (seg == 0)      v = w0[k * 128 + nn];
    else if (seg == 1) v = w1[k * 128 + nn];
    else if (seg == 2) v = (nn < 64) ? wm1[k * 64 + nn] : wv1[k * 64 + (nn - 64)];
    else v = (k < 64 && nn < 64) ? wm2[k * 64 + nn]
           : (k >= 64 && nn >= 64) ? wv2[(k - 64) * 64 + (nn - 64)] : 0.f;
    _Float16* dst = (seg == 0) ? d0 : (seg == 1) ? d1 : (seg == 2) ? dh1 : dh2;
    dst[li] = (_Float16)v;
    return;
  }

  // ---- block-local two-pass binning
  const int lo = blockIdx.x * CHUNK, hi = min(lo + CHUNK, e);
  for (int j = t; j < 392; j += 256) cnt[j] = 0;
  __syncthreads();
  for (int i = lo + t; i < hi; i += 256)
    atomicAdd(&cnt[rows[i] >> 7], 1);
  __syncthreads();
  for (int j = t; j < 392; j += 256)
    if (cnt[j] > 0) cur[j] = atomicAdd(&bcur[j * 16], cnt[j]);
  __syncthreads();
  for (int i = lo + t; i < hi; i += 256) {
    int r = rows[i];
    int b = r >> 7;
    int p = atomicAdd(&cur[b], 1);
    if (p < BCAP)
      bbuf[(size_t)b * BCAP + p] =
          make_uint2(((unsigned)(r & (RB - 1)) << 16) | (unsigned)cols[i],
                     __float_as_uint(vals[i]));
  }
}

// scan over bucket counts (nbk <= 512) -> bucket bases; also row_ptr[N] = E
__global__ __launch_bounds__(512)
void bscan_kernel(const int* __restrict__ bcur, int* __restrict__ bbase,
                  int* __restrict__ row_ptr, int nbk, int n) {
  __shared__ int s[512];
  int t = threadIdx.x;
  int c = (t < nbk) ? bcur[t * 16] : 0;
  s[t] = c;
  __syncthreads();
#pragma unroll
  for (int off = 1; off < 512; off <<= 1) {
    int a = (t >= off) ? s[t - off] : 0;
    __syncthreads();
    s[t] += a;
    __syncthreads();
  }
  if (t < nbk) bbase[t] = s[t] - c;
  if (t == 511) row_ptr[n] = s[511];
}

// ---------------------------------------------------------------- buildB
// Blocks [0, nbk): bucketB — per-bucket (128 rows) LDS hist+scan -> row_ptr;
// per-row col-sort (R16); LDS-staged coalesced CSR flush (~21.5 KB LDS).
// Blocks [nbk, nbk+GB): gemm_l1 — support1 = x@W0 (independent; overlaps).
__global__ __launch_bounds__(256)
void buildB_kernel(const uint2* __restrict__ bbuf, const int* __restrict__ bcur,
                   const int* __restrict__ bbase, int* __restrict__ row_ptr,
                   int2* __restrict__ s_pack, int nbk, int n,
                   const float* __restrict__ x, const _Float16* __restrict__ W0s,
                   _Float16* __restrict__ sup) {
  __shared__ int cnt[RB];
  __shared__ int scn[RB];
  __shared__ int2 stage[BCAP];

  if (blockIdx.x >= nbk) {
    gemm_l1(blockIdx.x - nbk, x, W0s, sup, n);
    return;
  }

  const int b = blockIdx.x, t = threadIdx.x;
  const int e = min(bcur[b * 16], BCAP);
  const int base = bbase[b];
  const uint2* src = bbuf + (size_t)b * BCAP;

  if (t < RB) cnt[t] = 0;
  __syncthreads();
  for (int i = t; i < e; i += 256)
    atomicAdd(&cnt[(src[i].x >> 16) & (RB - 1)], 1);
  __syncthreads();
  int c = (t < RB) ? cnt[t] : 0;
  if (t < RB) scn[t] = c;
  __syncthreads();
#pragma unroll
  for (int off = 1; off < RB; off <<= 1) {
    int a = (t >= off && t < RB) ? scn[t - off] : 0;
    __syncthreads();
    if (t < RB) scn[t] += a;
    __syncthreads();
  }
  if (t < RB) {
    int excl = scn[t] - c;
    int grow = b * RB + t;
    if (grow < n) row_ptr[grow] = base + excl;
    cnt[t] = excl;   // becomes per-row cursor
  }
  __syncthreads();
  for (int i = t; i < e; i += 256) {
    uint2 u = src[i];
    int pos = atomicAdd(&cnt[(u.x >> 16) & (RB - 1)], 1);
    stage[pos] = make_int2((int)(u.x & 0xFFFFu), (int)u.y);
  }
  __syncthreads();
  // ---- R16: sort each row's segment by col (1 thread/row, LDS insertion
  //      sort; segments disjoint). Enables the phase-coherent col sweep.
  if (t < RB) {
    const int lo2 = scn[t] - c, hi2 = scn[t];
    for (int a = lo2 + 1; a < hi2; ++a) {
      int2 key = stage[a];
      int bp = a - 1;
      while (bp >= lo2 && stage[bp].x > key.x) {
        stage[bp + 1] = stage[bp];
        --bp;
      }
      stage[bp + 1] = key;
    }
  }
  __syncthreads();
  for (int i = t; i < e; i += 256)
    s_pack[base + i] = stage[i];
}

// ---------------------------------------------------------------- fused SpMM+GEMM
// Phase 1 (R10 gather core): 16 lanes/row, half8/lane, 16 rows/block,
// unroll 4. h = relu(agg + gbias) -> LDS (padded 136) -> MFMA vs swizzled
// weights (A-frag pattern identical to gemm16, m89-verified).
// HEADS=false: emit support2 = h@W1swz. HEADS=true: t = relu(h@W1swz+[hb]),
// out = t@W2swz+[ob], split fp32 stores.
template<bool HEADS>
__global__ __launch_bounds__(256)
void spmm_fused(const half8* __restrict__ sup, const int* __restrict__ row_ptr,
                const int2* __restrict__ s_pack, const float* __restrict__ gbias,
                const _Float16* __restrict__ W1swz, const _Float16* __restrict__ W2swz,
                const float* __restrict__ hb0, const float* __restrict__ hb1,
                const float* __restrict__ ob0, const float* __restrict__ ob1,
                _Float16* __restrict__ outA, float* __restrict__ outM,
                float* __restrict__ outV, int n) {
  __shared__ _Float16 hs[16][136];
  __shared__ _Float16 ts[HEADS ? 16 : 1][136];
  const int t = threadIdx.x;
  const int g = t >> 4;
  const int l = t & 15;                 // feats [8l, 8l+8)
  int r = blockIdx.x * 16 + g;
  if (r >= n) r = n - 1;                // N%16==0 in practice; stores guarded
  const int beg = row_ptr[r], end = row_ptr[r + 1];

  // ---- gather
  float acc[8] = {};
  int i = beg;
  for (; i + 3 < end; i += 4) {
    int2 e0 = s_pack[i], e1 = s_pack[i + 1], e2 = s_pack[i + 2], e3 = s_pack[i + 3];
    half8 g0 = sup[(size_t)e0.x * 16 + l];
    half8 g1 = sup[(size_t)e1.x * 16 + l];
    half8 g2 = sup[(size_t)e2.x * 16 + l];
    half8 g3 = sup[(size_t)e3.x * 16 + l];
    float v0 = __int_as_float(e0.y), v1 = __int_as_float(e1.y);
    float v2 = __int_as_float(e2.y), v3 = __int_as_float(e3.y);
#pragma unroll
    for (int jj = 0; jj < 8; ++jj) acc[jj] = fmaf(v0, (float)g0[jj], acc[jj]);
#pragma unroll
    for (int jj = 0; jj < 8; ++jj) acc[jj] = fmaf(v1, (float)g1[jj], acc[jj]);
#pragma unroll
    for (int jj = 0; jj < 8; ++jj) acc[jj] = fmaf(v2, (float)g2[jj], acc[jj]);
#pragma unroll
    for (int jj = 0; jj < 8; ++jj) acc[jj] = fmaf(v3, (float)g3[jj], acc[jj]);
  }
  for (; i < end; ++i) {
    int2 e0 = s_pack[i];
    float v = __int_as_float(e0.y);
    half8 gg = sup[(size_t)e0.x * 16 + l];
#pragma unroll
    for (int jj = 0; jj < 8; ++jj) acc[jj] = fmaf(v, (float)gg[jj], acc[jj]);
  }

  // ---- h = relu(acc + gbias) -> LDS tile
  float4 b0 = *(const float4*)(gbias + 8 * l);
  float4 b1 = *(const float4*)(gbias + 8 * l + 4);
  _Float16* hp = &hs[g][8 * l];
  hp[0] = (_Float16)fmaxf(acc[0] + b0.x, 0.f);
  hp[1] = (_Float16)fmaxf(acc[1] + b0.y, 0.f);
  hp[2] = (_Float16)fmaxf(acc[2] + b0.z, 0.f);
  hp[3] = (_Float16)fmaxf(acc[3] + b0.w, 0.f);
  hp[4] = (_Float16)fmaxf(acc[4] + b1.x, 0.f);
  hp[5] = (_Float16)fmaxf(acc[5] + b1.y, 0.f);
  hp[6] = (_Float16)fmaxf(acc[6] + b1.z, 0.f);
  hp[7] = (_Float16)fmaxf(acc[7] + b1.w, 0.f);
  __syncthreads();

  // ---- MFMA phase: wave handles cols [wave*32, wave*32+32)
  const int lane = t & 63, wave = t >> 6;
  const int quad = lane >> 4, l16 = lane & 15;
  floatx4 cacc[2] = {{0.f, 0.f, 0.f, 0.f}, {0.f, 0.f, 0.f, 0.f}};
#pragma unroll
  for (int ks = 0; ks < 4; ++ks) {
    half8 a = *(const half8*)&hs[l16][ks * 32 + quad * 8];
#pragma unroll
    for (int nt = 0; nt < 2; ++nt) {
      int ntg = wave * 2 + nt;
      half8 b = *(const half8*)(W1swz + ((size_t)(ks * 8 + ntg) * 64 + lane) * 8);
      cacc[nt] = __builtin_amdgcn_mfma_f32_16x16x32_f16(a, b, cacc[nt], 0, 0, 0);
    }
  }

  if constexpr (!HEADS) {
#pragma unroll
    for (int nt = 0; nt < 2; ++nt) {
      int col = wave * 32 + nt * 16 + l16;
#pragma unroll
      for (int rr = 0; rr < 4; ++rr) {
        int row = blockIdx.x * 16 + quad * 4 + rr;
        if (row < n) outA[(size_t)row * 128 + col] = (_Float16)cacc[nt][rr];
      }
    }
  } else {
#pragma unroll
    for (int nt = 0; nt < 2; ++nt) {
      int col = wave * 32 + nt * 16 + l16;
      float bv = (col < 64) ? hb0[col] : hb1[col - 64];
#pragma unroll
      for (int rr = 0; rr < 4; ++rr)
        ts[quad * 4 + rr][col] = (_Float16)fmaxf(cacc[nt][rr] + bv, 0.f);
    }
    __syncthreads();
    floatx4 oacc[2] = {{0.f, 0.f, 0.f, 0.f}, {0.f, 0.f, 0.f, 0.f}};
#pragma unroll
    for (int ks = 0; ks < 4; ++ks) {
      half8 a = *(const half8*)&ts[l16][ks * 32 + quad * 8];
#pragma unroll
      for (int nt = 0; nt < 2; ++nt) {
        int ntg = wave * 2 + nt;
        half8 b = *(const half8*)(W2swz + ((size_t)(ks * 8 + ntg) * 64 + lane) * 8);
        oacc[nt] = __builtin_amdgcn_mfma_f32_16x16x32_f16(a, b, oacc[nt], 0, 0, 0);
      }
    }
#pragma unroll
    for (int nt = 0; nt < 2; ++nt) {
      int col = wave * 32 + nt * 16 + l16;
      float bv = (col < 64) ? ob0[col] : ob1[col - 64];
#pragma unroll
      for (int rr = 0; rr < 4; ++rr) {
        int row = blockIdx.x * 16 + quad * 4 + rr;
        if (row < n) {
          float v = oacc[nt][rr] + bv;
          if (col < 64) outM[(size_t)row * 64 + col] = v;
          else          outV[(size_t)row * 64 + (col - 64)] = v;
        }
      }
    }
  }
}

// ---------------------------------------------------------------- launch
extern "C" void kernel_launch(void* const* d_in, const int* in_sizes, int n_in,
                              void* d_out, int out_size, void* d_ws, size_t ws_size,
                              hipStream_t stream) {
  const float* x        = (const float*)d_in[0];
  const int*   edge_row = (const int*)d_in[1];
  const int*   edge_col = (const int*)d_in[2];
  const float* edge_val = (const float*)d_in[3];
  const float* W_gc0 = (const float*)d_in[4];
  const float* b_gc0 = (const float*)d_in[5];
  const float* W_gc1 = (const float*)d_in[6];
  const float* b_gc1 = (const float*)d_in[7];
  const float* Wm1 = (const float*)d_in[8];
  const float* bm1 = (const float*)d_in[9];
  const float* Wm2 = (const float*)d_in[10];
  const float* bm2 = (const float*)d_in[11];
  const float* Wv1 = (const float*)d_in[12];
  const float* bv1 = (const float*)d_in[13];
  const float* Wv2 = (const float*)d_in[14];
  const float* bv2 = (const float*)d_in[15];

  const int N = in_sizes[0] / 128;   // 50000
  const int E = in_sizes[1];         // 800000
  const int NBK = (N + RB - 1) / RB; // buckets (391)

  // workspace layout
  char* ws = (char*)d_ws;
  _Float16* bufA16 = (_Float16*)(ws);                            // N*128 f16 (support1)
  _Float16* bufB16 = (_Float16*)(ws + (size_t)N * 256);          // N*128 f16 (support2)
  int2*  s_pack = (int2*)(ws + (size_t)N * 512);                 // E*8
  char*  p = ws + (size_t)N * 512 + (size_t)E * 8;
  int*   row_ptr = (int*)p;           p += 200064;
  int*   bcur    = (int*)p;           p += (size_t)NBK * 64;     // 64B-padded counters
  int*   bbase   = (int*)p;           p += 2048;
  uint2* bbuf    = (uint2*)p;         p += (size_t)NBK * BCAP * 8;  // ~8 MB
  _Float16* W0s  = (_Float16*)p;      p += 32768;
  _Float16* W1s  = (_Float16*)p;      p += 32768;
  _Float16* Wh1s = (_Float16*)p;      p += 32768;
  _Float16* Wh2s = (_Float16*)p;      p += 32768;

  float* out_mean = (float*)d_out;
  float* out_lvar = out_mean + (size_t)N * 64;

  // ---- build: binning || weight swizzle
  hipMemsetAsync(bcur, 0, (size_t)NBK * 64, stream);
  const int binBlocks = (E + CHUNK - 1) / CHUNK;   // 391
  buildA_kernel<<<binBlocks + 256, 256, 0, stream>>>(
      edge_row, edge_col, edge_val, bcur, bbuf, E, binBlocks,
      W_gc0, W_gc1, Wm1, Wv1, Wm2, Wv2, W0s, W1s, Wh1s, Wh2s);
  bscan_kernel<<<1, 512, 0, stream>>>(bcur, bbase, row_ptr, NBK, N);

  const int GB = (N + 127) / 128;  // gemm blocks (391)
  const int SB = (N + 15) / 16;    // spmm blocks (3125)

  // ---- CSR flush (+ per-row col sort) || support1 = x@W0
  buildB_kernel<<<NBK + GB, 256, 0, stream>>>(bbuf, bcur, bbase, row_ptr, s_pack,
                                              NBK, N, x, W0s, bufA16);
  // ---- fused: h1 = relu(agg(support1)+b0); support2 = h1@W1
  spmm_fused<false><<<SB, 256, 0, stream>>>((const half8*)bufA16, row_ptr, s_pack,
                                            b_gc0, W1s, nullptr,
                                            nullptr, nullptr, nullptr, nullptr,
                                            bufB16, nullptr, nullptr, N);
  // ---- fused: h2 = relu(agg(support2)+b1); t = relu(h2@Wh1+[bm1|bv1]);
  //             out = t@Wh2 + [bm2|bv2], split
  spmm_fused<true><<<SB, 256, 0, stream>>>((const half8*)bufB16, row_ptr, s_pack,
                                           b_gc1, Wh1s, Wh2s,
                                           bm1, bv1, bm2, bv2,
                                           nullptr, out_mean, out_lvar, N);
}

// Round 8
// 237.551 us; speedup vs baseline: 1.0678x; 1.0678x over previous
//
#include <hip/hip_runtime.h>
#include <type_traits>

// GCNEncoder: h1 = relu(SpMM(x@W0) + b0); h2 = relu(SpMM(h1@W1) + b1)
// mean = relu(h2@Wm1+bm1)@Wm2+bm2 ; logvar = relu(h2@Wv1+bv1)@Wv2+bv2
// R5: f16 pipeline, MFMA GEMMs. R7: block-local two-pass binning.
// R8: fused heads, fp32-A GEMM, half8 SpMM. R10: GEMM 2 A-frags/wave.
// R11 (FAILED +26): feature-chunked SpMM — line granularity + XCD
//      replication nullified residency; halved MLP. Gather is miss-BW-bound
//      with a partial latency component (2x MLP gave +25%).
// R12 (FAILED +11): bundled {unroll8, NT-load, NT-store, fused build} —
//      NT-store on stage outputs evicted the next consumer's input from L2.
// R13 (WIN -32.7, 218.9us): fused row-local GEMMs into spmm blocks.
// R14 (FAILED +13.7): degree-balanced rperm — serial tail + sort overhead.
// R15 (WIN -6.1, 212.8us): buildA = blockbin || wconv; buildB = bucketB ||
//      gemm-L1 (co-resident overlap). 8 -> 6 dispatches.
// R16 (FAILED +40.8): per-row col insertion sort — buildB 66us, 1.45M LDS
//      bank conflicts (serial sort), and no spmm gain (sweep decoheres with
//      degree variance; no line reuse). Sort reverted.
// R17: R15 + {unroll-8 gather, NT-load on s_pack} — R12's bundle minus the
//      poisoned NT-store member. 8x16B outstanding/lane; edge stream marked
//      evict-first so it doesn't displace the 12.8MB support hot-set in L2.

typedef _Float16 half8 __attribute__((ext_vector_type(8)));
typedef float floatx4 __attribute__((ext_vector_type(4)));

#define BCAP 2560   // bucket capacity; mean 2048, sigma ~45 -> +11 sigma
#define CHUNK 2048  // edges per binning block
#define RB 128      // rows per bucket

// ---------------------------------------------------------------- gemm L1 (device)
// support1 = x(f32)@W0swz -> f16. R10 structure: 4 waves x 2 A-frags (32 rows),
// NT=8, KS=4. Wswz frag order [(ks*8+nt)*64+lane]*8+j, k=ks*32+quad*8+j,
// n=nt*16+(lane&15). C/D: col=lane&15, row=quad*4+reg (m89-verified).
__device__ void gemm_l1(int bid, const float* __restrict__ A,
                        const _Float16* __restrict__ Wswz,
                        _Float16* __restrict__ C0, int n) {
  const int t = threadIdx.x;
  const int lane = t & 63, wave = t >> 6;
  const int quad = lane >> 4, l16 = lane & 15;
  const int r_base = bid * 128 + wave * 32;

  int arow0 = r_base + l16;
  int arow1 = r_base + 16 + l16;
  if (arow0 >= n) arow0 = n - 1;        // clamp; clamped rows never stored
  if (arow1 >= n) arow1 = n - 1;
  const float* Ap0 = A + (size_t)arow0 * 128 + quad * 8;
  const float* Ap1 = A + (size_t)arow1 * 128 + quad * 8;

  floatx4 acc[2][8] = {};

#pragma unroll
  for (int ks = 0; ks < 4; ++ks) {
    float4 u = *(const float4*)(Ap0 + ks * 32);
    float4 w = *(const float4*)(Ap0 + ks * 32 + 4);
    half8 a0 = half8{(_Float16)u.x, (_Float16)u.y, (_Float16)u.z, (_Float16)u.w,
                     (_Float16)w.x, (_Float16)w.y, (_Float16)w.z, (_Float16)w.w};
    float4 u1 = *(const float4*)(Ap1 + ks * 32);
    float4 w1 = *(const float4*)(Ap1 + ks * 32 + 4);
    half8 a1 = half8{(_Float16)u1.x, (_Float16)u1.y, (_Float16)u1.z, (_Float16)u1.w,
                     (_Float16)w1.x, (_Float16)w1.y, (_Float16)w1.z, (_Float16)w1.w};
#pragma unroll
    for (int nt = 0; nt < 8; ++nt) {
      half8 b = *(const half8*)(Wswz + ((size_t)(ks * 8 + nt) * 64 + lane) * 8);
      acc[0][nt] = __builtin_amdgcn_mfma_f32_16x16x32_f16(a0, b, acc[0][nt], 0, 0, 0);
      acc[1][nt] = __builtin_amdgcn_mfma_f32_16x16x32_f16(a1, b, acc[1][nt], 0, 0, 0);
    }
  }

#pragma unroll
  for (int h = 0; h < 2; ++h) {
#pragma unroll
    for (int nt = 0; nt < 8; ++nt) {
      const int col = nt * 16 + l16;
#pragma unroll
      for (int r = 0; r < 4; ++r) {
        int row = r_base + h * 16 + quad * 4 + r;
        if (row < n) C0[(size_t)row * 128 + col] = (_Float16)acc[h][nt][r];
      }
    }
  }
}

// ---------------------------------------------------------------- buildA
// Blocks [0, binBlocks): block-local two-pass binning.
// Blocks [binBlocks, binBlocks+256): weight swizzle (4 segs).
__global__ __launch_bounds__(256)
void buildA_kernel(const int* __restrict__ rows, const int* __restrict__ cols,
                   const float* __restrict__ vals,
                   int* __restrict__ bcur, uint2* __restrict__ bbuf, int e,
                   int binBlocks,
                   const float* __restrict__ w0, const float* __restrict__ w1,
                   const float* __restrict__ wm1, const float* __restrict__ wv1,
                   const float* __restrict__ wm2, const float* __restrict__ wv2,
                   _Float16* __restrict__ d0, _Float16* __restrict__ d1,
                   _Float16* __restrict__ dh1, _Float16* __restrict__ dh2) {
  __shared__ int cnt[392];
  __shared__ int cur[392];
  const int t = threadIdx.x;

  if (blockIdx.x >= binBlocks) {
    // ---- weight conversion (swizzle to MFMA fragment order)
    int i = (blockIdx.x - binBlocks) * 256 + t;
    if (i >= 65536) return;
    int seg = i >> 14, li = i & 16383;
    int j = li & 7, lane = (li >> 3) & 63, tt = li >> 9;
    int nt = tt & 7, ks = tt >> 3;         // NT=8, KS=4
    int k = ks * 32 + (lane >> 4) * 8 + j;
    int nn = nt * 16 + (lane & 15);
    float v;
    if (seg == 0)      v = w0[k * 128 + nn];
    else if (seg == 1) v = w1[k * 128 + nn];
    else if (seg == 2) v = (nn < 64) ? wm1[k * 64 + nn] : wv1[k * 64 + (nn - 64)];
    else v = (k < 64 && nn < 64) ? wm2[k * 64 + nn]
           : (k >= 64 && nn >= 64) ? wv2[(k - 64) * 64 + (nn - 64)] : 0.f;
    _Float16* dst = (seg == 0) ? d0 : (seg == 1) ? d1 : (seg == 2) ? dh1 : dh2;
    dst[li] = (_Float16)v;
    return;
  }

  // ---- block-local two-pass binning
  const int lo = blockIdx.x * CHUNK, hi = min(lo + CHUNK, e);
  for (int j = t; j < 392; j += 256) cnt[j] = 0;
  __syncthreads();
  for (int i = lo + t; i < hi; i += 256)
    atomicAdd(&cnt[rows[i] >> 7], 1);
  __syncthreads();
  for (int j = t; j < 392; j += 256)
    if (cnt[j] > 0) cur[j] = atomicAdd(&bcur[j * 16], cnt[j]);
  __syncthreads();
  for (int i = lo + t; i < hi; i += 256) {
    int r = rows[i];
    int b = r >> 7;
    int p = atomicAdd(&cur[b], 1);
    if (p < BCAP)
      bbuf[(size_t)b * BCAP + p] =
          make_uint2(((unsigned)(r & (RB - 1)) << 16) | (unsigned)cols[i],
                     __float_as_uint(vals[i]));
  }
}

// scan over bucket counts (nbk <= 512) -> bucket bases; also row_ptr[N] = E
__global__ __launch_bounds__(512)
void bscan_kernel(const int* __restrict__ bcur, int* __restrict__ bbase,
                  int* __restrict__ row_ptr, int nbk, int n) {
  __shared__ int s[512];
  int t = threadIdx.x;
  int c = (t < nbk) ? bcur[t * 16] : 0;
  s[t] = c;
  __syncthreads();
#pragma unroll
  for (int off = 1; off < 512; off <<= 1) {
    int a = (t >= off) ? s[t - off] : 0;
    __syncthreads();
    s[t] += a;
    __syncthreads();
  }
  if (t < nbk) bbase[t] = s[t] - c;
  if (t == 511) row_ptr[n] = s[511];
}

// ---------------------------------------------------------------- buildB
// Blocks [0, nbk): bucketB — per-bucket (128 rows) LDS hist+scan -> row_ptr;
// LDS-staged coalesced CSR flush (~21.5 KB LDS).
// Blocks [nbk, nbk+GB): gemm_l1 — support1 = x@W0 (independent; overlaps).
__global__ __launch_bounds__(256)
void buildB_kernel(const uint2* __restrict__ bbuf, const int* __restrict__ bcur,
                   const int* __restrict__ bbase, int* __restrict__ row_ptr,
                   int2* __restrict__ s_pack, int nbk, int n,
                   const float* __restrict__ x, const _Float16* __restrict__ W0s,
                   _Float16* __restrict__ sup) {
  __shared__ int cnt[RB];
  __shared__ int scn[RB];
  __shared__ int2 stage[BCAP];

  if (blockIdx.x >= nbk) {
    gemm_l1(blockIdx.x - nbk, x, W0s, sup, n);
    return;
  }

  const int b = blockIdx.x, t = threadIdx.x;
  const int e = min(bcur[b * 16], BCAP);
  const int base = bbase[b];
  const uint2* src = bbuf + (size_t)b * BCAP;

  if (t < RB) cnt[t] = 0;
  __syncthreads();
  for (int i = t; i < e; i += 256)
    atomicAdd(&cnt[(src[i].x >> 16) & (RB - 1)], 1);
  __syncthreads();
  int c = (t < RB) ? cnt[t] : 0;
  if (t < RB) scn[t] = c;
  __syncthreads();
#pragma unroll
  for (int off = 1; off < RB; off <<= 1) {
    int a = (t >= off && t < RB) ? scn[t - off] : 0;
    __syncthreads();
    if (t < RB) scn[t] += a;
    __syncthreads();
  }
  if (t < RB) {
    int excl = scn[t] - c;
    int grow = b * RB + t;
    if (grow < n) row_ptr[grow] = base + excl;
    cnt[t] = excl;   // becomes per-row cursor
  }
  __syncthreads();
  for (int i = t; i < e; i += 256) {
    uint2 u = src[i];
    int pos = atomicAdd(&cnt[(u.x >> 16) & (RB - 1)], 1);
    stage[pos] = make_int2((int)(u.x & 0xFFFFu), (int)u.y);
  }
  __syncthreads();
  for (int i = t; i < e; i += 256)
    s_pack[base + i] = stage[i];
}

// ---------------------------------------------------------------- fused SpMM+GEMM
// Phase 1 gather: 16 lanes/row, half8 (16B) per lane, 16 rows/block,
// unroll 8 -> 8x16B outstanding gathers/lane (R17). s_pack read via NT
// loads (evict-first; don't displace support hot-set in L2). NO NT stores.
// h = relu(agg + gbias) -> LDS (padded 136) -> MFMA vs swizzled weights
// (A-frag pattern identical to gemm16, m89-verified).
// HEADS=false: emit support2 = h@W1swz. HEADS=true: t = relu(h@W1swz+[hb]),
// out = t@W2swz+[ob], split fp32 stores.
template<bool HEADS>
__global__ __launch_bounds__(256)
void spmm_fused(const half8* __restrict__ sup, const int* __restrict__ row_ptr,
                const int2* __restrict__ s_pack, const float* __restrict__ gbias,
                const _Float16* __restrict__ W1swz, const _Float16* __restrict__ W2swz,
                const float* __restrict__ hb0, const float* __restrict__ hb1,
                const float* __restrict__ ob0, const float* __restrict__ ob1,
                _Float16* __restrict__ outA, float* __restrict__ outM,
                float* __restrict__ outV, int n) {
  __shared__ _Float16 hs[16][136];
  __shared__ _Float16 ts[HEADS ? 16 : 1][136];
  const int t = threadIdx.x;
  const int g = t >> 4;
  const int l = t & 15;                 // feats [8l, 8l+8)
  int r = blockIdx.x * 16 + g;
  if (r >= n) r = n - 1;                // N%16==0 in practice; stores guarded
  const int beg = row_ptr[r], end = row_ptr[r + 1];
  const long long* ep = (const long long*)s_pack;

  // ---- gather (unroll 8, NT edge-stream loads)
  float acc[8] = {};
  int i = beg;
  for (; i + 7 < end; i += 8) {
    long long p0 = __builtin_nontemporal_load(ep + i);
    long long p1 = __builtin_nontemporal_load(ep + i + 1);
    long long p2 = __builtin_nontemporal_load(ep + i + 2);
    long long p3 = __builtin_nontemporal_load(ep + i + 3);
    long long p4 = __builtin_nontemporal_load(ep + i + 4);
    long long p5 = __builtin_nontemporal_load(ep + i + 5);
    long long p6 = __builtin_nontemporal_load(ep + i + 6);
    long long p7 = __builtin_nontemporal_load(ep + i + 7);
    half8 g0 = sup[(size_t)(int)p0 * 16 + l];
    half8 g1 = sup[(size_t)(int)p1 * 16 + l];
    half8 g2 = sup[(size_t)(int)p2 * 16 + l];
    half8 g3 = sup[(size_t)(int)p3 * 16 + l];
    half8 g4 = sup[(size_t)(int)p4 * 16 + l];
    half8 g5 = sup[(size_t)(int)p5 * 16 + l];
    half8 g6 = sup[(size_t)(int)p6 * 16 + l];
    half8 g7 = sup[(size_t)(int)p7 * 16 + l];
    float v0 = __int_as_float((int)(p0 >> 32));
    float v1 = __int_as_float((int)(p1 >> 32));
    float v2 = __int_as_float((int)(p2 >> 32));
    float v3 = __int_as_float((int)(p3 >> 32));
    float v4 = __int_as_float((int)(p4 >> 32));
    float v5 = __int_as_float((int)(p5 >> 32));
    float v6 = __int_as_float((int)(p6 >> 32));
    float v7 = __int_as_float((int)(p7 >> 32));
#pragma unroll
    for (int jj = 0; jj < 8; ++jj) acc[jj] = fmaf(v0, (float)g0[jj], acc[jj]);
#pragma unroll
    for (int jj = 0; jj < 8; ++jj) acc[jj] = fmaf(v1, (float)g1[jj], acc[jj]);
#pragma unroll
    for (int jj = 0; jj < 8; ++jj) acc[jj] = fmaf(v2, (float)g2[jj], acc[jj]);
#pragma unroll
    for (int jj = 0; jj < 8; ++jj) acc[jj] = fmaf(v3, (float)g3[jj], acc[jj]);
#pragma unroll
    for (int jj = 0; jj < 8; ++jj) acc[jj] = fmaf(v4, (float)g4[jj], acc[jj]);
#pragma unroll
    for (int jj = 0; jj < 8; ++jj) acc[jj] = fmaf(v5, (float)g5[jj], acc[jj]);
#pragma unroll
    for (int jj = 0; jj < 8; ++jj) acc[jj] = fmaf(v6, (float)g6[jj], acc[jj]);
#pragma unroll
    for (int jj = 0; jj < 8; ++jj) acc[jj] = fmaf(v7, (float)g7[jj], acc[jj]);
  }
  for (; i < end; ++i) {
    long long p0 = __builtin_nontemporal_load(ep + i);
    float v = __int_as_float((int)(p0 >> 32));
    half8 gg = sup[(size_t)(int)p0 * 16 + l];
#pragma unroll
    for (int jj = 0; jj < 8; ++jj) acc[jj] = fmaf(v, (float)gg[jj], acc[jj]);
  }

  // ---- h = relu(acc + gbias) -> LDS tile
  float4 b0 = *(const float4*)(gbias + 8 * l);
  float4 b1 = *(const float4*)(gbias + 8 * l + 4);
  _Float16* hp = &hs[g][8 * l];
  hp[0] = (_Float16)fmaxf(acc[0] + b0.x, 0.f);
  hp[1] = (_Float16)fmaxf(acc[1] + b0.y, 0.f);
  hp[2] = (_Float16)fmaxf(acc[2] + b0.z, 0.f);
  hp[3] = (_Float16)fmaxf(acc[3] + b0.w, 0.f);
  hp[4] = (_Float16)fmaxf(acc[4] + b1.x, 0.f);
  hp[5] = (_Float16)fmaxf(acc[5] + b1.y, 0.f);
  hp[6] = (_Float16)fmaxf(acc[6] + b1.z, 0.f);
  hp[7] = (_Float16)fmaxf(acc[7] + b1.w, 0.f);
  __syncthreads();

  // ---- MFMA phase: wave handles cols [wave*32, wave*32+32)
  const int lane = t & 63, wave = t >> 6;
  const int quad = lane >> 4, l16 = lane & 15;
  floatx4 cacc[2] = {{0.f, 0.f, 0.f, 0.f}, {0.f, 0.f, 0.f, 0.f}};
#pragma unroll
  for (int ks = 0; ks < 4; ++ks) {
    half8 a = *(const half8*)&hs[l16][ks * 32 + quad * 8];
#pragma unroll
    for (int nt = 0; nt < 2; ++nt) {
      int ntg = wave * 2 + nt;
      half8 b = *(const half8*)(W1swz + ((size_t)(ks * 8 + ntg) * 64 + lane) * 8);
      cacc[nt] = __builtin_amdgcn_mfma_f32_16x16x32_f16(a, b, cacc[nt], 0, 0, 0);
    }
  }

  if constexpr (!HEADS) {
#pragma unroll
    for (int nt = 0; nt < 2; ++nt) {
      int col = wave * 32 + nt * 16 + l16;
#pragma unroll
      for (int rr = 0; rr < 4; ++rr) {
        int row = blockIdx.x * 16 + quad * 4 + rr;
        if (row < n) outA[(size_t)row * 128 + col] = (_Float16)cacc[nt][rr];
      }
    }
  } else {
#pragma unroll
    for (int nt = 0; nt < 2; ++nt) {
      int col = wave * 32 + nt * 16 + l16;
      float bv = (col < 64) ? hb0[col] : hb1[col - 64];
#pragma unroll
      for (int rr = 0; rr < 4; ++rr)
        ts[quad * 4 + rr][col] = (_Float16)fmaxf(cacc[nt][rr] + bv, 0.f);
    }
    __syncthreads();
    floatx4 oacc[2] = {{0.f, 0.f, 0.f, 0.f}, {0.f, 0.f, 0.f, 0.f}};
#pragma unroll
    for (int ks = 0; ks < 4; ++ks) {
      half8 a = *(const half8*)&ts[l16][ks * 32 + quad * 8];
#pragma unroll
      for (int nt = 0; nt < 2; ++nt) {
        int ntg = wave * 2 + nt;
        half8 b = *(const half8*)(W2swz + ((size_t)(ks * 8 + ntg) * 64 + lane) * 8);
        oacc[nt] = __builtin_amdgcn_mfma_f32_16x16x32_f16(a, b, oacc[nt], 0, 0, 0);
      }
    }
#pragma unroll
    for (int nt = 0; nt < 2; ++nt) {
      int col = wave * 32 + nt * 16 + l16;
      float bv = (col < 64) ? ob0[col] : ob1[col - 64];
#pragma unroll
      for (int rr = 0; rr < 4; ++rr) {
        int row = blockIdx.x * 16 + quad * 4 + rr;
        if (row < n) {
          float v = oacc[nt][rr] + bv;
          if (col < 64) outM[(size_t)row * 64 + col] = v;
          else          outV[(size_t)row * 64 + (col - 64)] = v;
        }
      }
    }
  }
}

// ---------------------------------------------------------------- launch
extern "C" void kernel_launch(void* const* d_in, const int* in_sizes, int n_in,
                              void* d_out, int out_size, void* d_ws, size_t ws_size,
                              hipStream_t stream) {
  const float* x        = (const float*)d_in[0];
  const int*   edge_row = (const int*)d_in[1];
  const int*   edge_col = (const int*)d_in[2];
  const float* edge_val = (const float*)d_in[3];
  const float* W_gc0 = (const float*)d_in[4];
  const float* b_gc0 = (const float*)d_in[5];
  const float* W_gc1 = (const float*)d_in[6];
  const float* b_gc1 = (const float*)d_in[7];
  const float* Wm1 = (const float*)d_in[8];
  const float* bm1 = (const float*)d_in[9];
  const float* Wm2 = (const float*)d_in[10];
  const float* bm2 = (const float*)d_in[11];
  const float* Wv1 = (const float*)d_in[12];
  const float* bv1 = (const float*)d_in[13];
  const float* Wv2 = (const float*)d_in[14];
  const float* bv2 = (const float*)d_in[15];

  const int N = in_sizes[0] / 128;   // 50000
  const int E = in_sizes[1];         // 800000
  const int NBK = (N + RB - 1) / RB; // buckets (391)

  // workspace layout
  char* ws = (char*)d_ws;
  _Float16* bufA16 = (_Float16*)(ws);                            // N*128 f16 (support1)
  _Float16* bufB16 = (_Float16*)(ws + (size_t)N * 256);          // N*128 f16 (support2)
  int2*  s_pack = (int2*)(ws + (size_t)N * 512);                 // E*8
  char*  p = ws + (size_t)N * 512 + (size_t)E * 8;
  int*   row_ptr = (int*)p;           p += 200064;
  int*   bcur    = (int*)p;           p += (size_t)NBK * 64;     // 64B-padded counters
  int*   bbase   = (int*)p;           p += 2048;
  uint2* bbuf    = (uint2*)p;         p += (size_t)NBK * BCAP * 8;  // ~8 MB
  _Float16* W0s  = (_Float16*)p;      p += 32768;
  _Float16* W1s  = (_Float16*)p;      p += 32768;
  _Float16* Wh1s = (_Float16*)p;      p += 32768;
  _Float16* Wh2s = (_Float16*)p;      p += 32768;

  float* out_mean = (float*)d_out;
  float* out_lvar = out_mean + (size_t)N * 64;

  // ---- build: binning || weight swizzle
  hipMemsetAsync(bcur, 0, (size_t)NBK * 64, stream);
  const int binBlocks = (E + CHUNK - 1) / CHUNK;   // 391
  buildA_kernel<<<binBlocks + 256, 256, 0, stream>>>(
      edge_row, edge_col, edge_val, bcur, bbuf, E, binBlocks,
      W_gc0, W_gc1, Wm1, Wv1, Wm2, Wv2, W0s, W1s, Wh1s, Wh2s);
  bscan_kernel<<<1, 512, 0, stream>>>(bcur, bbase, row_ptr, NBK, N);

  const int GB = (N + 127) / 128;  // gemm blocks (391)
  const int SB = (N + 15) / 16;    // spmm blocks (3125)

  // ---- CSR flush || support1 = x@W0 (independent; co-resident overlap)
  buildB_kernel<<<NBK + GB, 256, 0, stream>>>(bbuf, bcur, bbase, row_ptr, s_pack,
                                              NBK, N, x, W0s, bufA16);
  // ---- fused: h1 = relu(agg(support1)+b0); support2 = h1@W1
  spmm_fused<false><<<SB, 256, 0, stream>>>((const half8*)bufA16, row_ptr, s_pack,
                                            b_gc0, W1s, nullptr,
                                            nullptr, nullptr, nullptr, nullptr,
                                            bufB16, nullptr, nullptr, N);
  // ---- fused: h2 = relu(agg(support2)+b1); t = relu(h2@Wh1+[bm1|bv1]);
  //             out = t@Wh2 + [bm2|bv2], split
  spmm_fused<true><<<SB, 256, 0, stream>>>((const half8*)bufB16, row_ptr, s_pack,
                                           b_gc1, Wh1s, Wh2s,
                                           bm1, bv1, bm2, bv2,
                                           nullptr, out_mean, out_lvar, N);
}

// Round 9
// 210.180 us; speedup vs baseline: 1.2069x; 1.1302x over previous
//
#include <hip/hip_runtime.h>
#include <type_traits>

// GCNEncoder: h1 = relu(SpMM(x@W0) + b0); h2 = relu(SpMM(h1@W1) + b1)
// mean = relu(h2@Wm1+bm1)@Wm2+bm2 ; logvar = relu(h2@Wv1+bv1)@Wv2+bv2
// R5: f16 pipeline, MFMA GEMMs. R7: block-local two-pass binning.
// R8: fused heads, fp32-A GEMM, half8 SpMM. R10: GEMM 2 A-frags/wave.
// R11 (FAILED +26): feature-chunked SpMM — line granularity + XCD
//      replication nullified residency.
// R12 (FAILED +11): bundled {unroll8, NT hints, fused build}.
// R13 (WIN -32.7, 218.9us): fused row-local GEMMs into spmm blocks.
// R14 (FAILED +13.7): degree-balanced rperm — serial tail + sort overhead.
// R15 (WIN -6.1, 212.8us): buildA = blockbin || wconv; buildB = bucketB ||
//      gemm-L1. 6 dispatches.
// R16 (FAILED +40.8): per-row col sort — 1.45M LDS conflicts, no spmm gain.
// R17 (FAILED +24.7): unroll-8 + NT-load gather — spmm 41->54us. MORE MLP
//      HURTS: gather is L2-miss-BW-bound (FETCH 88MB vs 19 ideal, ~2TB/s
//      fabric). spmm ~41us is within ~10% of its structural floor; the
//      random-graph hot-set (12.8MB) can't fit per-XCD L2 (4MB). Reverted.
// R18: exact R15 compute kernels; build-chain shave: (a) bscan fused into
//      bucketB (per-block prefix, refcheck-validated in R11/R12), (b)
//      single-pass binning (edges held in regs: hist->reserve->scatter,
//      drops one 6.4MB rows re-read). 6 -> 5 dispatches.

typedef _Float16 half8 __attribute__((ext_vector_type(8)));
typedef float floatx4 __attribute__((ext_vector_type(4)));

#define BCAP 2560   // bucket capacity; mean 2048, sigma ~45 -> +11 sigma
#define CHUNK 2048  // edges per binning block
#define RB 128      // rows per bucket

// ---------------------------------------------------------------- gemm L1 (device)
// support1 = x(f32)@W0swz -> f16. R10 structure: 4 waves x 2 A-frags (32 rows),
// NT=8, KS=4. Wswz frag order [(ks*8+nt)*64+lane]*8+j, k=ks*32+quad*8+j,
// n=nt*16+(lane&15). C/D: col=lane&15, row=quad*4+reg (m89-verified).
__device__ void gemm_l1(int bid, const float* __restrict__ A,
                        const _Float16* __restrict__ Wswz,
                        _Float16* __restrict__ C0, int n) {
  const int t = threadIdx.x;
  const int lane = t & 63, wave = t >> 6;
  const int quad = lane >> 4, l16 = lane & 15;
  const int r_base = bid * 128 + wave * 32;

  int arow0 = r_base + l16;
  int arow1 = r_base + 16 + l16;
  if (arow0 >= n) arow0 = n - 1;        // clamp; clamped rows never stored
  if (arow1 >= n) arow1 = n - 1;
  const float* Ap0 = A + (size_t)arow0 * 128 + quad * 8;
  const float* Ap1 = A + (size_t)arow1 * 128 + quad * 8;

  floatx4 acc[2][8] = {};

#pragma unroll
  for (int ks = 0; ks < 4; ++ks) {
    float4 u = *(const float4*)(Ap0 + ks * 32);
    float4 w = *(const float4*)(Ap0 + ks * 32 + 4);
    half8 a0 = half8{(_Float16)u.x, (_Float16)u.y, (_Float16)u.z, (_Float16)u.w,
                     (_Float16)w.x, (_Float16)w.y, (_Float16)w.z, (_Float16)w.w};
    float4 u1 = *(const float4*)(Ap1 + ks * 32);
    float4 w1 = *(const float4*)(Ap1 + ks * 32 + 4);
    half8 a1 = half8{(_Float16)u1.x, (_Float16)u1.y, (_Float16)u1.z, (_Float16)u1.w,
                     (_Float16)w1.x, (_Float16)w1.y, (_Float16)w1.z, (_Float16)w1.w};
#pragma unroll
    for (int nt = 0; nt < 8; ++nt) {
      half8 b = *(const half8*)(Wswz + ((size_t)(ks * 8 + nt) * 64 + lane) * 8);
      acc[0][nt] = __builtin_amdgcn_mfma_f32_16x16x32_f16(a0, b, acc[0][nt], 0, 0, 0);
      acc[1][nt] = __builtin_amdgcn_mfma_f32_16x16x32_f16(a1, b, acc[1][nt], 0, 0, 0);
    }
  }

#pragma unroll
  for (int h = 0; h < 2; ++h) {
#pragma unroll
    for (int nt = 0; nt < 8; ++nt) {
      const int col = nt * 16 + l16;
#pragma unroll
      for (int r = 0; r < 4; ++r) {
        int row = r_base + h * 16 + quad * 4 + r;
        if (row < n) C0[(size_t)row * 128 + col] = (_Float16)acc[h][nt][r];
      }
    }
  }
}

// ---------------------------------------------------------------- buildA
// Blocks [0, binBlocks): single-pass block-local binning (edges in regs).
// Blocks [binBlocks, binBlocks+256): weight swizzle (4 segs).
__global__ __launch_bounds__(256)
void buildA_kernel(const int* __restrict__ rows, const int* __restrict__ cols,
                   const float* __restrict__ vals,
                   int* __restrict__ bcur, uint2* __restrict__ bbuf, int e,
                   int binBlocks,
                   const float* __restrict__ w0, const float* __restrict__ w1,
                   const float* __restrict__ wm1, const float* __restrict__ wv1,
                   const float* __restrict__ wm2, const float* __restrict__ wv2,
                   _Float16* __restrict__ d0, _Float16* __restrict__ d1,
                   _Float16* __restrict__ dh1, _Float16* __restrict__ dh2) {
  __shared__ int cnt[392];
  __shared__ int cur[392];
  const int t = threadIdx.x;

  if (blockIdx.x >= binBlocks) {
    // ---- weight conversion (swizzle to MFMA fragment order)
    int i = (blockIdx.x - binBlocks) * 256 + t;
    if (i >= 65536) return;
    int seg = i >> 14, li = i & 16383;
    int j = li & 7, lane = (li >> 3) & 63, tt = li >> 9;
    int nt = tt & 7, ks = tt >> 3;         // NT=8, KS=4
    int k = ks * 32 + (lane >> 4) * 8 + j;
    int nn = nt * 16 + (lane & 15);
    float v;
    if (seg == 0)      v = w0[k * 128 + nn];
    else if (seg == 1) v = w1[k * 128 + nn];
    else if (seg == 2) v = (nn < 64) ? wm1[k * 64 + nn] : wv1[k * 64 + (nn - 64)];
    else v = (k < 64 && nn < 64) ? wm2[k * 64 + nn]
           : (k >= 64 && nn >= 64) ? wv2[(k - 64) * 64 + (nn - 64)] : 0.f;
    _Float16* dst = (seg == 0) ? d0 : (seg == 1) ? d1 : (seg == 2) ? dh1 : dh2;
    dst[li] = (_Float16)v;
    return;
  }

  // ---- single-pass block-local binning (CHUNK/256 = 8 edges per thread)
  const int lo = blockIdx.x * CHUNK, hi = min(lo + CHUNK, e);
  int myr[8], myc[8];
  float myv[8];
  int nk = 0;
  for (int i = lo + t; i < hi; i += 256, ++nk) {
    myr[nk] = rows[i];
    myc[nk] = cols[i];
    myv[nk] = vals[i];
  }
  for (int j = t; j < 392; j += 256) cnt[j] = 0;
  __syncthreads();
  for (int k = 0; k < nk; ++k)
    atomicAdd(&cnt[myr[k] >> 7], 1);
  __syncthreads();
  for (int j = t; j < 392; j += 256)
    if (cnt[j] > 0) cur[j] = atomicAdd(&bcur[j * 16], cnt[j]);
  __syncthreads();
  for (int k = 0; k < nk; ++k) {
    int r = myr[k];
    int b = r >> 7;
    int p = atomicAdd(&cur[b], 1);
    if (p < BCAP)
      bbuf[(size_t)b * BCAP + p] =
          make_uint2(((unsigned)(r & (RB - 1)) << 16) | (unsigned)myc[k],
                     __float_as_uint(myv[k]));
  }
}

// ---------------------------------------------------------------- buildB
// Blocks [0, nbk): bucketB — fused bucket-base prefix (over bcur), per-bucket
// LDS hist+scan -> row_ptr; LDS-staged coalesced CSR flush (~22.5 KB LDS).
// Blocks [nbk, nbk+GB): gemm_l1 — support1 = x@W0 (independent; overlaps).
__global__ __launch_bounds__(256)
void buildB_kernel(const uint2* __restrict__ bbuf, const int* __restrict__ bcur,
                   int* __restrict__ row_ptr, int2* __restrict__ s_pack,
                   int nbk, int n, int e_total,
                   const float* __restrict__ x, const _Float16* __restrict__ W0s,
                   _Float16* __restrict__ sup) {
  __shared__ int cnt[RB];
  __shared__ int scn[RB];
  __shared__ int red[256];
  __shared__ int2 stage[BCAP];

  if (blockIdx.x >= nbk) {
    gemm_l1(blockIdx.x - nbk, x, W0s, sup, n);
    return;
  }

  const int b = blockIdx.x, t = threadIdx.x;

  // fused exclusive prefix over bucket counts (nbk <= 512 -> <=2 loads/thread)
  int partial = 0;
  for (int j = t; j < b; j += 256) partial += bcur[j * 16];
  red[t] = partial;
  __syncthreads();
#pragma unroll
  for (int off = 128; off > 0; off >>= 1) {
    if (t < off) red[t] += red[t + off];
    __syncthreads();
  }
  const int base = red[0];

  const int e = min(bcur[b * 16], BCAP);
  const uint2* src = bbuf + (size_t)b * BCAP;

  if (t < RB) cnt[t] = 0;
  __syncthreads();
  for (int i = t; i < e; i += 256)
    atomicAdd(&cnt[(src[i].x >> 16) & (RB - 1)], 1);
  __syncthreads();
  int c = (t < RB) ? cnt[t] : 0;
  if (t < RB) scn[t] = c;
  __syncthreads();
#pragma unroll
  for (int off = 1; off < RB; off <<= 1) {
    int a = (t >= off && t < RB) ? scn[t - off] : 0;
    __syncthreads();
    if (t < RB) scn[t] += a;
    __syncthreads();
  }
  if (t < RB) {
    int excl = scn[t] - c;
    int grow = b * RB + t;
    if (grow < n) row_ptr[grow] = base + excl;
    cnt[t] = excl;   // becomes per-row cursor
  }
  if (b == 0 && t == 0) row_ptr[n] = e_total;
  __syncthreads();
  for (int i = t; i < e; i += 256) {
    uint2 u = src[i];
    int pos = atomicAdd(&cnt[(u.x >> 16) & (RB - 1)], 1);
    stage[pos] = make_int2((int)(u.x & 0xFFFFu), (int)u.y);
  }
  __syncthreads();
  for (int i = t; i < e; i += 256)
    s_pack[base + i] = stage[i];
}

// ---------------------------------------------------------------- fused SpMM+GEMM
// Phase 1 (R10 gather core): 16 lanes/row, half8/lane, 16 rows/block,
// unroll 4, plain loads. h = relu(agg + gbias) -> LDS (padded 136) -> MFMA
// vs swizzled weights (A-frag pattern identical to gemm16, m89-verified).
// HEADS=false: emit support2 = h@W1swz. HEADS=true: t = relu(h@W1swz+[hb]),
// out = t@W2swz+[ob], split fp32 stores.
template<bool HEADS>
__global__ __launch_bounds__(256)
void spmm_fused(const half8* __restrict__ sup, const int* __restrict__ row_ptr,
                const int2* __restrict__ s_pack, const float* __restrict__ gbias,
                const _Float16* __restrict__ W1swz, const _Float16* __restrict__ W2swz,
                const float* __restrict__ hb0, const float* __restrict__ hb1,
                const float* __restrict__ ob0, const float* __restrict__ ob1,
                _Float16* __restrict__ outA, float* __restrict__ outM,
                float* __restrict__ outV, int n) {
  __shared__ _Float16 hs[16][136];
  __shared__ _Float16 ts[HEADS ? 16 : 1][136];
  const int t = threadIdx.x;
  const int g = t >> 4;
  const int l = t & 15;                 // feats [8l, 8l+8)
  int r = blockIdx.x * 16 + g;
  if (r >= n) r = n - 1;                // N%16==0 in practice; stores guarded
  const int beg = row_ptr[r], end = row_ptr[r + 1];

  // ---- gather
  float acc[8] = {};
  int i = beg;
  for (; i + 3 < end; i += 4) {
    int2 e0 = s_pack[i], e1 = s_pack[i + 1], e2 = s_pack[i + 2], e3 = s_pack[i + 3];
    half8 g0 = sup[(size_t)e0.x * 16 + l];
    half8 g1 = sup[(size_t)e1.x * 16 + l];
    half8 g2 = sup[(size_t)e2.x * 16 + l];
    half8 g3 = sup[(size_t)e3.x * 16 + l];
    float v0 = __int_as_float(e0.y), v1 = __int_as_float(e1.y);
    float v2 = __int_as_float(e2.y), v3 = __int_as_float(e3.y);
#pragma unroll
    for (int jj = 0; jj < 8; ++jj) acc[jj] = fmaf(v0, (float)g0[jj], acc[jj]);
#pragma unroll
    for (int jj = 0; jj < 8; ++jj) acc[jj] = fmaf(v1, (float)g1[jj], acc[jj]);
#pragma unroll
    for (int jj = 0; jj < 8; ++jj) acc[jj] = fmaf(v2, (float)g2[jj], acc[jj]);
#pragma unroll
    for (int jj = 0; jj < 8; ++jj) acc[jj] = fmaf(v3, (float)g3[jj], acc[jj]);
  }
  for (; i < end; ++i) {
    int2 e0 = s_pack[i];
    float v = __int_as_float(e0.y);
    half8 gg = sup[(size_t)e0.x * 16 + l];
#pragma unroll
    for (int jj = 0; jj < 8; ++jj) acc[jj] = fmaf(v, (float)gg[jj], acc[jj]);
  }

  // ---- h = relu(acc + gbias) -> LDS tile
  float4 b0 = *(const float4*)(gbias + 8 * l);
  float4 b1 = *(const float4*)(gbias + 8 * l + 4);
  _Float16* hp = &hs[g][8 * l];
  hp[0] = (_Float16)fmaxf(acc[0] + b0.x, 0.f);
  hp[1] = (_Float16)fmaxf(acc[1] + b0.y, 0.f);
  hp[2] = (_Float16)fmaxf(acc[2] + b0.z, 0.f);
  hp[3] = (_Float16)fmaxf(acc[3] + b0.w, 0.f);
  hp[4] = (_Float16)fmaxf(acc[4] + b1.x, 0.f);
  hp[5] = (_Float16)fmaxf(acc[5] + b1.y, 0.f);
  hp[6] = (_Float16)fmaxf(acc[6] + b1.z, 0.f);
  hp[7] = (_Float16)fmaxf(acc[7] + b1.w, 0.f);
  __syncthreads();

  // ---- MFMA phase: wave handles cols [wave*32, wave*32+32)
  const int lane = t & 63, wave = t >> 6;
  const int quad = lane >> 4, l16 = lane & 15;
  floatx4 cacc[2] = {{0.f, 0.f, 0.f, 0.f}, {0.f, 0.f, 0.f, 0.f}};
#pragma unroll
  for (int ks = 0; ks < 4; ++ks) {
    half8 a = *(const half8*)&hs[l16][ks * 32 + quad * 8];
#pragma unroll
    for (int nt = 0; nt < 2; ++nt) {
      int ntg = wave * 2 + nt;
      half8 b = *(const half8*)(W1swz + ((size_t)(ks * 8 + ntg) * 64 + lane) * 8);
      cacc[nt] = __builtin_amdgcn_mfma_f32_16x16x32_f16(a, b, cacc[nt], 0, 0, 0);
    }
  }

  if constexpr (!HEADS) {
#pragma unroll
    for (int nt = 0; nt < 2; ++nt) {
      int col = wave * 32 + nt * 16 + l16;
#pragma unroll
      for (int rr = 0; rr < 4; ++rr) {
        int row = blockIdx.x * 16 + quad * 4 + rr;
        if (row < n) outA[(size_t)row * 128 + col] = (_Float16)cacc[nt][rr];
      }
    }
  } else {
#pragma unroll
    for (int nt = 0; nt < 2; ++nt) {
      int col = wave * 32 + nt * 16 + l16;
      float bv = (col < 64) ? hb0[col] : hb1[col - 64];
#pragma unroll
      for (int rr = 0; rr < 4; ++rr)
        ts[quad * 4 + rr][col] = (_Float16)fmaxf(cacc[nt][rr] + bv, 0.f);
    }
    __syncthreads();
    floatx4 oacc[2] = {{0.f, 0.f, 0.f, 0.f}, {0.f, 0.f, 0.f, 0.f}};
#pragma unroll
    for (int ks = 0; ks < 4; ++ks) {
      half8 a = *(const half8*)&ts[l16][ks * 32 + quad * 8];
#pragma unroll
      for (int nt = 0; nt < 2; ++nt) {
        int ntg = wave * 2 + nt;
        half8 b = *(const half8*)(W2swz + ((size_t)(ks * 8 + ntg) * 64 + lane) * 8);
        oacc[nt] = __builtin_amdgcn_mfma_f32_16x16x32_f16(a, b, oacc[nt], 0, 0, 0);
      }
    }
#pragma unroll
    for (int nt = 0; nt < 2; ++nt) {
      int col = wave * 32 + nt * 16 + l16;
      float bv = (col < 64) ? ob0[col] : ob1[col - 64];
#pragma unroll
      for (int rr = 0; rr < 4; ++rr) {
        int row = blockIdx.x * 16 + quad * 4 + rr;
        if (row < n) {
          float v = oacc[nt][rr] + bv;
          if (col < 64) outM[(size_t)row * 64 + col] = v;
          else          outV[(size_t)row * 64 + (col - 64)] = v;
        }
      }
    }
  }
}

// ---------------------------------------------------------------- launch
extern "C" void kernel_launch(void* const* d_in, const int* in_sizes, int n_in,
                              void* d_out, int out_size, void* d_ws, size_t ws_size,
                              hipStream_t stream) {
  const float* x        = (const float*)d_in[0];
  const int*   edge_row = (const int*)d_in[1];
  const int*   edge_col = (const int*)d_in[2];
  const float* edge_val = (const float*)d_in[3];
  const float* W_gc0 = (const float*)d_in[4];
  const float* b_gc0 = (const float*)d_in[5];
  const float* W_gc1 = (const float*)d_in[6];
  const float* b_gc1 = (const float*)d_in[7];
  const float* Wm1 = (const float*)d_in[8];
  const float* bm1 = (const float*)d_in[9];
  const float* Wm2 = (const float*)d_in[10];
  const float* bm2 = (const float*)d_in[11];
  const float* Wv1 = (const float*)d_in[12];
  const float* bv1 = (const float*)d_in[13];
  const float* Wv2 = (const float*)d_in[14];
  const float* bv2 = (const float*)d_in[15];

  const int N = in_sizes[0] / 128;   // 50000
  const int E = in_sizes[1];         // 800000
  const int NBK = (N + RB - 1) / RB; // buckets (391)

  // workspace layout
  char* ws = (char*)d_ws;
  _Float16* bufA16 = (_Float16*)(ws);                            // N*128 f16 (support1)
  _Float16* bufB16 = (_Float16*)(ws + (size_t)N * 256);          // N*128 f16 (support2)
  int2*  s_pack = (int2*)(ws + (size_t)N * 512);                 // E*8
  char*  p = ws + (size_t)N * 512 + (size_t)E * 8;
  int*   row_ptr = (int*)p;           p += 200064;
  int*   bcur    = (int*)p;           p += (size_t)NBK * 64;     // 64B-padded counters
  uint2* bbuf    = (uint2*)p;         p += (size_t)NBK * BCAP * 8;  // ~8 MB
  _Float16* W0s  = (_Float16*)p;      p += 32768;
  _Float16* W1s  = (_Float16*)p;      p += 32768;
  _Float16* Wh1s = (_Float16*)p;      p += 32768;
  _Float16* Wh2s = (_Float16*)p;      p += 32768;

  float* out_mean = (float*)d_out;
  float* out_lvar = out_mean + (size_t)N * 64;

  // ---- build: binning || weight swizzle
  hipMemsetAsync(bcur, 0, (size_t)NBK * 64, stream);
  const int binBlocks = (E + CHUNK - 1) / CHUNK;   // 391
  buildA_kernel<<<binBlocks + 256, 256, 0, stream>>>(
      edge_row, edge_col, edge_val, bcur, bbuf, E, binBlocks,
      W_gc0, W_gc1, Wm1, Wv1, Wm2, Wv2, W0s, W1s, Wh1s, Wh2s);

  const int GB = (N + 127) / 128;  // gemm blocks (391)
  const int SB = (N + 15) / 16;    // spmm blocks (3125)

  // ---- CSR flush (fused bucket-base prefix) || support1 = x@W0
  buildB_kernel<<<NBK + GB, 256, 0, stream>>>(bbuf, bcur, row_ptr, s_pack,
                                              NBK, N, E, x, W0s, bufA16);
  // ---- fused: h1 = relu(agg(support1)+b0); support2 = h1@W1
  spmm_fused<false><<<SB, 256, 0, stream>>>((const half8*)bufA16, row_ptr, s_pack,
                                            b_gc0, W1s, nullptr,
                                            nullptr, nullptr, nullptr, nullptr,
                                            bufB16, nullptr, nullptr, N);
  // ---- fused: h2 = relu(agg(support2)+b1); t = relu(h2@Wh1+[bm1|bv1]);
  //             out = t@Wh2 + [bm2|bv2], split
  spmm_fused<true><<<SB, 256, 0, stream>>>((const half8*)bufB16, row_ptr, s_pack,
                                           b_gc1, Wh1s, Wh2s,
                                           bm1, bv1, bm2, bv2,
                                           nullptr, out_mean, out_lvar, N);
}